// Round 1
// baseline (619.260 us; speedup 1.0000x reference)
//
#include <hip/hip_runtime.h>

// LiquidS4: y = (scan(a, u@B.T)) @ C.T + D*u
// shapes: u (4,4096,1024) f32; Lambda (64); log_dt (1); B (64,1024); C (1024,64); D (1024)

constexpr int BATCH = 4;
constexpr int L     = 4096;
constexpr int DM    = 1024;
constexpr int N     = 64;
constexpr int ROWS  = BATCH * L;   // 16384

// ---------------- Kernel 1: Bu[row,n] = sum_d u[row,d] * B[n,d] ----------------
// M=16384, K=1024, N=64. Tile 64 rows x 64 n, K-chunk 32. 256 threads, acc 4x4.
__global__ __launch_bounds__(256) void bu_gemm(const float* __restrict__ u,
                                               const float* __restrict__ Bm,
                                               float* __restrict__ Bu) {
  __shared__ float As[64][33];
  __shared__ float Bs[64][33];
  const int tid = threadIdx.x;
  const int tx = tid & 15;   // n-group
  const int ty = tid >> 4;   // row-group
  const int row0 = blockIdx.x * 64;

  float acc[4][4] = {};

  for (int k0 = 0; k0 < DM; k0 += 32) {
    // stage A tile: 64 rows x 32 k  (512 float4, 2 per thread)
    #pragma unroll
    for (int i = tid; i < 512; i += 256) {
      const int r = i >> 3, q = i & 7;
      const float4 v = *reinterpret_cast<const float4*>(
          &u[(long)(row0 + r) * DM + k0 + q * 4]);
      As[r][q * 4 + 0] = v.x; As[r][q * 4 + 1] = v.y;
      As[r][q * 4 + 2] = v.z; As[r][q * 4 + 3] = v.w;
    }
    // stage B tile: 64 n x 32 k
    #pragma unroll
    for (int i = tid; i < 512; i += 256) {
      const int r = i >> 3, q = i & 7;
      const float4 v = *reinterpret_cast<const float4*>(
          &Bm[(long)r * DM + k0 + q * 4]);
      Bs[r][q * 4 + 0] = v.x; Bs[r][q * 4 + 1] = v.y;
      Bs[r][q * 4 + 2] = v.z; Bs[r][q * 4 + 3] = v.w;
    }
    __syncthreads();

    #pragma unroll
    for (int k = 0; k < 32; ++k) {
      float av[4], bv[4];
      #pragma unroll
      for (int r = 0; r < 4; ++r) av[r] = As[ty * 4 + r][k];
      #pragma unroll
      for (int c = 0; c < 4; ++c) bv[c] = Bs[tx * 4 + c][k];
      #pragma unroll
      for (int r = 0; r < 4; ++r)
        #pragma unroll
        for (int c = 0; c < 4; ++c)
          acc[r][c] = fmaf(av[r], bv[c], acc[r][c]);
    }
    __syncthreads();
  }

  #pragma unroll
  for (int r = 0; r < 4; ++r) {
    const float4 v = make_float4(acc[r][0], acc[r][1], acc[r][2], acc[r][3]);
    *reinterpret_cast<float4*>(&Bu[(long)(row0 + ty * 4 + r) * N + tx * 4]) = v;
  }
}

// ---------------- Kernel 2: sequential diagonal recurrence ----------------
// x[b,t,n] = a[n]*x[b,t-1,n] + Bu[b,t,n].  One wave per batch, lane = n.
__global__ __launch_bounds__(64) void scan_kernel(const float* __restrict__ Bu,
                                                  const float* __restrict__ Lambda,
                                                  const float* __restrict__ log_dt,
                                                  float* __restrict__ xs) {
  const int b = blockIdx.x;
  const int n = threadIdx.x;
  const float dt = __expf(log_dt[0]);
  const float a  = __expf(-dt * __expf(Lambda[n]));

  const float* bu = Bu + (long)b * L * N + n;
  float*       xp = xs + (long)b * L * N + n;

  float x = 0.0f;
  #pragma unroll 4
  for (int t = 0; t < L; ++t) {
    x = fmaf(a, x, bu[(long)t * N]);
    xp[(long)t * N] = x;
  }
}

// ---------------- Kernel 3: y[row,d] = sum_n xs[row,n]*C[d,n] + D[d]*u[row,d] --
// M=16384, K=64, N=1024. Tile 64 rows x 64 d per block; K=64 fits one LDS tile.
__global__ __launch_bounds__(256) void y_gemm(const float* __restrict__ xs,
                                              const float* __restrict__ Cm,
                                              const float* __restrict__ Dv,
                                              const float* __restrict__ u,
                                              float* __restrict__ y) {
  __shared__ float Xs[64][65];
  __shared__ float Cs[64][65];
  const int tid = threadIdx.x;
  const int tx = tid & 15;   // d-group
  const int ty = tid >> 4;   // row-group
  const int rt = blockIdx.x & 255;   // 256 row tiles
  const int dt = blockIdx.x >> 8;    // 16 d tiles
  const int row0 = rt * 64;
  const int d0   = dt * 64;

  // stage xs tile: 64 rows x 64 n   (1024 float4, 4 per thread)
  #pragma unroll
  for (int i = tid; i < 1024; i += 256) {
    const int r = i >> 4, q = i & 15;
    const float4 v = *reinterpret_cast<const float4*>(
        &xs[(long)(row0 + r) * N + q * 4]);
    Xs[r][q * 4 + 0] = v.x; Xs[r][q * 4 + 1] = v.y;
    Xs[r][q * 4 + 2] = v.z; Xs[r][q * 4 + 3] = v.w;
  }
  // stage C tile: 64 d x 64 n
  #pragma unroll
  for (int i = tid; i < 1024; i += 256) {
    const int r = i >> 4, q = i & 15;
    const float4 v = *reinterpret_cast<const float4*>(
        &Cm[(long)(d0 + r) * N + q * 4]);
    Cs[r][q * 4 + 0] = v.x; Cs[r][q * 4 + 1] = v.y;
    Cs[r][q * 4 + 2] = v.z; Cs[r][q * 4 + 3] = v.w;
  }
  __syncthreads();

  float acc[4][4] = {};
  #pragma unroll 8
  for (int k = 0; k < 64; ++k) {
    float av[4], bv[4];
    #pragma unroll
    for (int r = 0; r < 4; ++r) av[r] = Xs[ty * 4 + r][k];
    #pragma unroll
    for (int c = 0; c < 4; ++c) bv[c] = Cs[tx * 4 + c][k];
    #pragma unroll
    for (int r = 0; r < 4; ++r)
      #pragma unroll
      for (int c = 0; c < 4; ++c)
        acc[r][c] = fmaf(av[r], bv[c], acc[r][c]);
  }

  // epilogue: + D*u, float4 coalesced store
  #pragma unroll
  for (int r = 0; r < 4; ++r) {
    const int row = row0 + ty * 4 + r;
    const float4 uu = *reinterpret_cast<const float4*>(&u[(long)row * DM + d0 + tx * 4]);
    const float4 dd = *reinterpret_cast<const float4*>(&Dv[d0 + tx * 4]);
    float4 o;
    o.x = fmaf(dd.x, uu.x, acc[r][0]);
    o.y = fmaf(dd.y, uu.y, acc[r][1]);
    o.z = fmaf(dd.z, uu.z, acc[r][2]);
    o.w = fmaf(dd.w, uu.w, acc[r][3]);
    *reinterpret_cast<float4*>(&y[(long)row * DM + d0 + tx * 4]) = o;
  }
}

extern "C" void kernel_launch(void* const* d_in, const int* in_sizes, int n_in,
                              void* d_out, int out_size, void* d_ws, size_t ws_size,
                              hipStream_t stream) {
  const float* u      = (const float*)d_in[0];
  const float* Lambda = (const float*)d_in[1];
  const float* log_dt = (const float*)d_in[2];
  const float* Bm     = (const float*)d_in[3];
  const float* Cm     = (const float*)d_in[4];
  const float* Dv     = (const float*)d_in[5];
  float* y = (float*)d_out;

  float* Bu = (float*)d_ws;                 // 16384*64 f32 = 4 MB
  float* xs = Bu + (long)ROWS * N;          // 4 MB

  bu_gemm<<<ROWS / 64, 256, 0, stream>>>(u, Bm, Bu);
  scan_kernel<<<BATCH, N, 0, stream>>>(Bu, Lambda, log_dt, xs);
  y_gemm<<<(ROWS / 64) * (DM / 64), 256, 0, stream>>>(xs, Cm, Dv, u, y);
}

// Round 2
// 149.156 us; speedup vs baseline: 4.1518x; 4.1518x over previous
//
#include <hip/hip_runtime.h>

// LiquidS4: y = (scan(a, u@B.T)) @ C.T + D*u
// shapes: u (4,4096,1024) f32; Lambda (64); log_dt (1); B (64,1024); C (1024,64); D (1024)

constexpr int BATCH  = 4;
constexpr int L      = 4096;
constexpr int DM     = 1024;
constexpr int N      = 64;
constexpr int ROWS   = BATCH * L;   // 16384
constexpr int CHUNK  = 64;          // timesteps per scan chunk
constexpr int NCHUNK = L / CHUNK;   // 64

// ---------------- Kernel 1: Bu[row,n] = sum_d u[row,d] * B[n,d] ----------------
__global__ __launch_bounds__(256) void bu_gemm(const float* __restrict__ u,
                                               const float* __restrict__ Bm,
                                               float* __restrict__ Bu) {
  __shared__ float As[64][33];
  __shared__ float Bs[64][33];
  const int tid = threadIdx.x;
  const int tx = tid & 15;   // n-group
  const int ty = tid >> 4;   // row-group
  const int row0 = blockIdx.x * 64;

  float acc[4][4] = {};

  for (int k0 = 0; k0 < DM; k0 += 32) {
    #pragma unroll
    for (int i = tid; i < 512; i += 256) {
      const int r = i >> 3, q = i & 7;
      const float4 v = *reinterpret_cast<const float4*>(
          &u[(long)(row0 + r) * DM + k0 + q * 4]);
      As[r][q * 4 + 0] = v.x; As[r][q * 4 + 1] = v.y;
      As[r][q * 4 + 2] = v.z; As[r][q * 4 + 3] = v.w;
    }
    #pragma unroll
    for (int i = tid; i < 512; i += 256) {
      const int r = i >> 3, q = i & 7;
      const float4 v = *reinterpret_cast<const float4*>(
          &Bm[(long)r * DM + k0 + q * 4]);
      Bs[r][q * 4 + 0] = v.x; Bs[r][q * 4 + 1] = v.y;
      Bs[r][q * 4 + 2] = v.z; Bs[r][q * 4 + 3] = v.w;
    }
    __syncthreads();

    #pragma unroll
    for (int k = 0; k < 32; ++k) {
      float av[4], bv[4];
      #pragma unroll
      for (int r = 0; r < 4; ++r) av[r] = As[ty * 4 + r][k];
      #pragma unroll
      for (int c = 0; c < 4; ++c) bv[c] = Bs[tx * 4 + c][k];
      #pragma unroll
      for (int r = 0; r < 4; ++r)
        #pragma unroll
        for (int c = 0; c < 4; ++c)
          acc[r][c] = fmaf(av[r], bv[c], acc[r][c]);
    }
    __syncthreads();
  }

  #pragma unroll
  for (int r = 0; r < 4; ++r) {
    const float4 v = make_float4(acc[r][0], acc[r][1], acc[r][2], acc[r][3]);
    *reinterpret_cast<float4*>(&Bu[(long)(row0 + ty * 4 + r) * N + tx * 4]) = v;
  }
}

// ---------------- Kernel 2: chunk-local scan ----------------
// Block (b,c): lane n scans CHUNK steps with x0=0 entirely in registers.
// Writes local prefixes to xsl and the chunk-final value to F[b][c][n].
__global__ __launch_bounds__(64) void local_scan(const float* __restrict__ Bu,
                                                 const float* __restrict__ Lambda,
                                                 const float* __restrict__ log_dt,
                                                 float* __restrict__ xsl,
                                                 float* __restrict__ F) {
  const int b = blockIdx.x >> 6;      // /NCHUNK
  const int c = blockIdx.x & 63;      // %NCHUNK
  const int n = threadIdx.x;
  const float dt = __expf(log_dt[0]);
  const float a  = __expf(-dt * __expf(Lambda[n]));

  const long base = ((long)b * L + (long)c * CHUNK) * N + n;
  const float* bu = Bu + base;
  float*       xp = xsl + base;

  float v[CHUNK];
  #pragma unroll
  for (int s = 0; s < CHUNK; ++s) v[s] = bu[s * N];   // independent coalesced loads

  float x = 0.0f;
  #pragma unroll
  for (int s = 0; s < CHUNK; ++s) { x = fmaf(a, x, v[s]); v[s] = x; }

  #pragma unroll
  for (int s = 0; s < CHUNK; ++s) xp[s * N] = v[s];

  F[((b << 6) + c) * N + n] = x;   // chunk-final state
}

// ---------------- Kernel 3: sequential scan over chunk finals ----------------
// carry_in[b][c][n] = state entering chunk c:  P_c = a^CHUNK * P_{c-1} + F_c.
__global__ __launch_bounds__(256) void carry_scan(const float* __restrict__ F,
                                                  const float* __restrict__ Lambda,
                                                  const float* __restrict__ log_dt,
                                                  float* __restrict__ carry_in) {
  const int t = threadIdx.x;
  const int b = t >> 6;
  const int n = t & 63;
  const float dt = __expf(log_dt[0]);
  const float w  = -dt * __expf(Lambda[n]);
  const float aS = __expf(w * (float)CHUNK);

  float f[NCHUNK];
  #pragma unroll
  for (int c = 0; c < NCHUNK; ++c) f[c] = F[((b << 6) + c) * N + n];

  float P = 0.0f;
  #pragma unroll
  for (int c = 0; c < NCHUNK; ++c) {
    carry_in[((b << 6) + c) * N + n] = P;
    P = fmaf(aS, P, f[c]);
  }
}

// ---------------- Kernel 4: y = xs @ C.T + D*u, with carry fixup fused --------
// xs_true[row0+r][n] = xsl[row0+r][n] + exp(w_n*(r+1)) * carry_in[b][c][n]
__global__ __launch_bounds__(256) void y_gemm(const float* __restrict__ xsl,
                                              const float* __restrict__ carry_in,
                                              const float* __restrict__ Lambda,
                                              const float* __restrict__ log_dt,
                                              const float* __restrict__ Cm,
                                              const float* __restrict__ Dv,
                                              const float* __restrict__ u,
                                              float* __restrict__ y) {
  __shared__ float Xs[64][65];
  __shared__ float Cs[64][65];
  __shared__ float wS[64];
  __shared__ float ciS[64];
  const int tid = threadIdx.x;
  const int tx = tid & 15;          // d-group
  const int ty = tid >> 4;          // row-group
  const int rt = blockIdx.x & 255;  // 256 row tiles
  const int dtile = blockIdx.x >> 8;
  const int row0 = rt * 64;
  const int d0   = dtile * 64;
  const int b    = row0 >> 12;          // / L
  const int c    = (row0 & (L - 1)) >> 6;

  if (tid < 64) {
    const float dt = __expf(log_dt[0]);
    wS[tid]  = -dt * __expf(Lambda[tid]);
    ciS[tid] = carry_in[((b << 6) + c) * N + tid];
  }
  __syncthreads();

  // stage xs tile with fixup: 64 rows x 64 n
  #pragma unroll
  for (int i = tid; i < 1024; i += 256) {
    const int r = i >> 4, q = i & 15;
    float4 v = *reinterpret_cast<const float4*>(
        &xsl[(long)(row0 + r) * N + q * 4]);
    const float p = (float)(r + 1);
    v.x += __expf(wS[q * 4 + 0] * p) * ciS[q * 4 + 0];
    v.y += __expf(wS[q * 4 + 1] * p) * ciS[q * 4 + 1];
    v.z += __expf(wS[q * 4 + 2] * p) * ciS[q * 4 + 2];
    v.w += __expf(wS[q * 4 + 3] * p) * ciS[q * 4 + 3];
    Xs[r][q * 4 + 0] = v.x; Xs[r][q * 4 + 1] = v.y;
    Xs[r][q * 4 + 2] = v.z; Xs[r][q * 4 + 3] = v.w;
  }
  // stage C tile: 64 d x 64 n
  #pragma unroll
  for (int i = tid; i < 1024; i += 256) {
    const int r = i >> 4, q = i & 15;
    const float4 v = *reinterpret_cast<const float4*>(
        &Cm[(long)(d0 + r) * N + q * 4]);
    Cs[r][q * 4 + 0] = v.x; Cs[r][q * 4 + 1] = v.y;
    Cs[r][q * 4 + 2] = v.z; Cs[r][q * 4 + 3] = v.w;
  }
  __syncthreads();

  float acc[4][4] = {};
  #pragma unroll 8
  for (int k = 0; k < 64; ++k) {
    float av[4], bv[4];
    #pragma unroll
    for (int r = 0; r < 4; ++r) av[r] = Xs[ty * 4 + r][k];
    #pragma unroll
    for (int cc = 0; cc < 4; ++cc) bv[cc] = Cs[tx * 4 + cc][k];
    #pragma unroll
    for (int r = 0; r < 4; ++r)
      #pragma unroll
      for (int cc = 0; cc < 4; ++cc)
        acc[r][cc] = fmaf(av[r], bv[cc], acc[r][cc]);
  }

  #pragma unroll
  for (int r = 0; r < 4; ++r) {
    const int row = row0 + ty * 4 + r;
    const float4 uu = *reinterpret_cast<const float4*>(&u[(long)row * DM + d0 + tx * 4]);
    const float4 dd = *reinterpret_cast<const float4*>(&Dv[d0 + tx * 4]);
    float4 o;
    o.x = fmaf(dd.x, uu.x, acc[r][0]);
    o.y = fmaf(dd.y, uu.y, acc[r][1]);
    o.z = fmaf(dd.z, uu.z, acc[r][2]);
    o.w = fmaf(dd.w, uu.w, acc[r][3]);
    *reinterpret_cast<float4*>(&y[(long)row * DM + d0 + tx * 4]) = o;
  }
}

extern "C" void kernel_launch(void* const* d_in, const int* in_sizes, int n_in,
                              void* d_out, int out_size, void* d_ws, size_t ws_size,
                              hipStream_t stream) {
  const float* u      = (const float*)d_in[0];
  const float* Lambda = (const float*)d_in[1];
  const float* log_dt = (const float*)d_in[2];
  const float* Bm     = (const float*)d_in[3];
  const float* Cm     = (const float*)d_in[4];
  const float* Dv     = (const float*)d_in[5];
  float* y = (float*)d_out;

  float* Bu       = (float*)d_ws;                     // 4 MB
  float* xsl      = Bu + (long)ROWS * N;              // 4 MB
  float* F        = xsl + (long)ROWS * N;             // 64 KB
  float* carry_in = F + (long)BATCH * NCHUNK * N;     // 64 KB

  bu_gemm<<<ROWS / 64, 256, 0, stream>>>(u, Bm, Bu);
  local_scan<<<BATCH * NCHUNK, 64, 0, stream>>>(Bu, Lambda, log_dt, xsl, F);
  carry_scan<<<1, 256, 0, stream>>>(F, Lambda, log_dt, carry_in);
  y_gemm<<<(ROWS / 64) * (DM / 64), 256, 0, stream>>>(xsl, carry_in, Lambda, log_dt,
                                                      Cm, Dv, u, y);
}

// Round 3
// 100.714 us; speedup vs baseline: 6.1487x; 1.4810x over previous
//
#include <hip/hip_runtime.h>

// LiquidS4: y = (scan(a, u@B.T)) @ C.T + D*u
// shapes: u (4,4096,1024) f32; Lambda (64); log_dt (1); B (64,1024); C (1024,64); D (1024)

constexpr int BATCH  = 4;
constexpr int L      = 4096;
constexpr int DM     = 1024;
constexpr int N      = 64;
constexpr int ROWS   = BATCH * L;   // 16384
constexpr int CHUNK  = 64;          // timesteps per scan chunk
constexpr int NCHUNK = L / CHUNK;   // 64

// ---------------- Kernel 1: Bu[row,n] = sum_d u[row,d] * B[n,d] ----------------
// Tile 64 rows x 64 n, K-chunk 32. Transposed LDS [k][m] (stride 68 keeps 16B
// alignment: 68*4 % 16 == 0) so per-thread operands are contiguous -> ds_read_b128.
// Register double-buffer: load chunk c+1 during compute of chunk c.
__global__ __launch_bounds__(256) void bu_gemm(const float* __restrict__ u,
                                               const float* __restrict__ Bm,
                                               float* __restrict__ Bu) {
  __shared__ __align__(16) float As[2][32][68];   // [buf][k][row]
  __shared__ __align__(16) float Bs[2][32][68];   // [buf][k][n]
  const int tid = threadIdx.x;
  const int tx = tid & 15;   // n-group
  const int ty = tid >> 4;   // row-group
  const int row0 = blockIdx.x * 64;

  // staging: element i covers row r=i>>3, k-quad q=i&7 (one float4 = 4 k's)
  const int r0 = tid >> 3;          // rows 0..31
  const int q0 = tid & 7;
  const int r1 = r0 + 32;           // rows 32..63

  float acc[4][4] = {};
  float4 pa0, pa1, pb0, pb1;

  // prologue: chunk 0 -> regs -> LDS buf 0
  pa0 = *reinterpret_cast<const float4*>(&u[(long)(row0 + r0) * DM + q0 * 4]);
  pa1 = *reinterpret_cast<const float4*>(&u[(long)(row0 + r1) * DM + q0 * 4]);
  pb0 = *reinterpret_cast<const float4*>(&Bm[(long)r0 * DM + q0 * 4]);
  pb1 = *reinterpret_cast<const float4*>(&Bm[(long)r1 * DM + q0 * 4]);
  #pragma unroll
  for (int jj = 0; jj < 4; ++jj) {
    As[0][q0 * 4 + jj][r0] = (&pa0.x)[jj];
    As[0][q0 * 4 + jj][r1] = (&pa1.x)[jj];
    Bs[0][q0 * 4 + jj][r0] = (&pb0.x)[jj];
    Bs[0][q0 * 4 + jj][r1] = (&pb1.x)[jj];
  }

  constexpr int NCH = DM / 32;   // 32 chunks
  for (int c = 0; c < NCH; ++c) {
    const int buf = c & 1;
    if (c + 1 < NCH) {
      const int kn = (c + 1) * 32;
      pa0 = *reinterpret_cast<const float4*>(&u[(long)(row0 + r0) * DM + kn + q0 * 4]);
      pa1 = *reinterpret_cast<const float4*>(&u[(long)(row0 + r1) * DM + kn + q0 * 4]);
      pb0 = *reinterpret_cast<const float4*>(&Bm[(long)r0 * DM + kn + q0 * 4]);
      pb1 = *reinterpret_cast<const float4*>(&Bm[(long)r1 * DM + kn + q0 * 4]);
    }
    __syncthreads();   // buf fully written (by previous iter), buf^1 fully consumed

    #pragma unroll
    for (int k = 0; k < 32; ++k) {
      const float4 av = *reinterpret_cast<const float4*>(&As[buf][k][ty * 4]);
      const float4 bv = *reinterpret_cast<const float4*>(&Bs[buf][k][tx * 4]);
      acc[0][0] = fmaf(av.x, bv.x, acc[0][0]);
      acc[0][1] = fmaf(av.x, bv.y, acc[0][1]);
      acc[0][2] = fmaf(av.x, bv.z, acc[0][2]);
      acc[0][3] = fmaf(av.x, bv.w, acc[0][3]);
      acc[1][0] = fmaf(av.y, bv.x, acc[1][0]);
      acc[1][1] = fmaf(av.y, bv.y, acc[1][1]);
      acc[1][2] = fmaf(av.y, bv.z, acc[1][2]);
      acc[1][3] = fmaf(av.y, bv.w, acc[1][3]);
      acc[2][0] = fmaf(av.z, bv.x, acc[2][0]);
      acc[2][1] = fmaf(av.z, bv.y, acc[2][1]);
      acc[2][2] = fmaf(av.z, bv.z, acc[2][2]);
      acc[2][3] = fmaf(av.z, bv.w, acc[2][3]);
      acc[3][0] = fmaf(av.w, bv.x, acc[3][0]);
      acc[3][1] = fmaf(av.w, bv.y, acc[3][1]);
      acc[3][2] = fmaf(av.w, bv.z, acc[3][2]);
      acc[3][3] = fmaf(av.w, bv.w, acc[3][3]);
    }

    if (c + 1 < NCH) {
      const int nb = buf ^ 1;
      #pragma unroll
      for (int jj = 0; jj < 4; ++jj) {
        As[nb][q0 * 4 + jj][r0] = (&pa0.x)[jj];
        As[nb][q0 * 4 + jj][r1] = (&pa1.x)[jj];
        Bs[nb][q0 * 4 + jj][r0] = (&pb0.x)[jj];
        Bs[nb][q0 * 4 + jj][r1] = (&pb1.x)[jj];
      }
    }
  }

  #pragma unroll
  for (int r = 0; r < 4; ++r) {
    const float4 v = make_float4(acc[r][0], acc[r][1], acc[r][2], acc[r][3]);
    *reinterpret_cast<float4*>(&Bu[(long)(row0 + ty * 4 + r) * N + tx * 4]) = v;
  }
}

// ---------------- Kernel 2: chunk-local scan ----------------
__global__ __launch_bounds__(64) void local_scan(const float* __restrict__ Bu,
                                                 const float* __restrict__ Lambda,
                                                 const float* __restrict__ log_dt,
                                                 float* __restrict__ xsl,
                                                 float* __restrict__ F) {
  const int b = blockIdx.x >> 6;
  const int c = blockIdx.x & 63;
  const int n = threadIdx.x;
  const float dt = __expf(log_dt[0]);
  const float a  = __expf(-dt * __expf(Lambda[n]));

  const long base = ((long)b * L + (long)c * CHUNK) * N + n;
  const float* bu = Bu + base;
  float*       xp = xsl + base;

  float v[CHUNK];
  #pragma unroll
  for (int s = 0; s < CHUNK; ++s) v[s] = bu[s * N];

  float x = 0.0f;
  #pragma unroll
  for (int s = 0; s < CHUNK; ++s) { x = fmaf(a, x, v[s]); v[s] = x; }

  #pragma unroll
  for (int s = 0; s < CHUNK; ++s) xp[s * N] = v[s];

  F[((b << 6) + c) * N + n] = x;
}

// ---------------- Kernel 3: sequential scan over chunk finals ----------------
__global__ __launch_bounds__(256) void carry_scan(const float* __restrict__ F,
                                                  const float* __restrict__ Lambda,
                                                  const float* __restrict__ log_dt,
                                                  float* __restrict__ carry_in) {
  const int t = threadIdx.x;
  const int b = t >> 6;
  const int n = t & 63;
  const float dt = __expf(log_dt[0]);
  const float w  = -dt * __expf(Lambda[n]);
  const float aS = __expf(w * (float)CHUNK);

  float f[NCHUNK];
  #pragma unroll
  for (int c = 0; c < NCHUNK; ++c) f[c] = F[((b << 6) + c) * N + n];

  float P = 0.0f;
  #pragma unroll
  for (int c = 0; c < NCHUNK; ++c) {
    carry_in[((b << 6) + c) * N + n] = P;
    P = fmaf(aS, P, f[c]);
  }
}

// ---------------- Kernel 4: y = xs @ C.T + D*u, carry fixup fused -------------
__global__ __launch_bounds__(256) void y_gemm(const float* __restrict__ xsl,
                                              const float* __restrict__ carry_in,
                                              const float* __restrict__ Lambda,
                                              const float* __restrict__ log_dt,
                                              const float* __restrict__ Cm,
                                              const float* __restrict__ Dv,
                                              const float* __restrict__ u,
                                              float* __restrict__ y) {
  __shared__ float Xs[64][65];
  __shared__ float Cs[64][65];
  __shared__ float wS[64];
  __shared__ float ciS[64];
  const int tid = threadIdx.x;
  const int tx = tid & 15;
  const int ty = tid >> 4;
  const int rt = blockIdx.x & 255;
  const int dtile = blockIdx.x >> 8;
  const int row0 = rt * 64;
  const int d0   = dtile * 64;
  const int b    = row0 >> 12;
  const int c    = (row0 & (L - 1)) >> 6;

  if (tid < 64) {
    const float dt = __expf(log_dt[0]);
    wS[tid]  = -dt * __expf(Lambda[tid]);
    ciS[tid] = carry_in[((b << 6) + c) * N + tid];
  }
  __syncthreads();

  #pragma unroll
  for (int i = tid; i < 1024; i += 256) {
    const int r = i >> 4, q = i & 15;
    float4 v = *reinterpret_cast<const float4*>(
        &xsl[(long)(row0 + r) * N + q * 4]);
    const float p = (float)(r + 1);
    v.x += __expf(wS[q * 4 + 0] * p) * ciS[q * 4 + 0];
    v.y += __expf(wS[q * 4 + 1] * p) * ciS[q * 4 + 1];
    v.z += __expf(wS[q * 4 + 2] * p) * ciS[q * 4 + 2];
    v.w += __expf(wS[q * 4 + 3] * p) * ciS[q * 4 + 3];
    Xs[r][q * 4 + 0] = v.x; Xs[r][q * 4 + 1] = v.y;
    Xs[r][q * 4 + 2] = v.z; Xs[r][q * 4 + 3] = v.w;
  }
  #pragma unroll
  for (int i = tid; i < 1024; i += 256) {
    const int r = i >> 4, q = i & 15;
    const float4 v = *reinterpret_cast<const float4*>(
        &Cm[(long)(d0 + r) * N + q * 4]);
    Cs[r][q * 4 + 0] = v.x; Cs[r][q * 4 + 1] = v.y;
    Cs[r][q * 4 + 2] = v.z; Cs[r][q * 4 + 3] = v.w;
  }
  __syncthreads();

  float acc[4][4] = {};
  #pragma unroll 8
  for (int k = 0; k < 64; ++k) {
    float av[4], bv[4];
    #pragma unroll
    for (int r = 0; r < 4; ++r) av[r] = Xs[ty * 4 + r][k];
    #pragma unroll
    for (int cc = 0; cc < 4; ++cc) bv[cc] = Cs[tx * 4 + cc][k];
    #pragma unroll
    for (int r = 0; r < 4; ++r)
      #pragma unroll
      for (int cc = 0; cc < 4; ++cc)
        acc[r][cc] = fmaf(av[r], bv[cc], acc[r][cc]);
  }

  #pragma unroll
  for (int r = 0; r < 4; ++r) {
    const int row = row0 + ty * 4 + r;
    const float4 uu = *reinterpret_cast<const float4*>(&u[(long)row * DM + d0 + tx * 4]);
    const float4 dd = *reinterpret_cast<const float4*>(&Dv[d0 + tx * 4]);
    float4 o;
    o.x = fmaf(dd.x, uu.x, acc[r][0]);
    o.y = fmaf(dd.y, uu.y, acc[r][1]);
    o.z = fmaf(dd.z, uu.z, acc[r][2]);
    o.w = fmaf(dd.w, uu.w, acc[r][3]);
    *reinterpret_cast<float4*>(&y[(long)row * DM + d0 + tx * 4]) = o;
  }
}

extern "C" void kernel_launch(void* const* d_in, const int* in_sizes, int n_in,
                              void* d_out, int out_size, void* d_ws, size_t ws_size,
                              hipStream_t stream) {
  const float* u      = (const float*)d_in[0];
  const float* Lambda = (const float*)d_in[1];
  const float* log_dt = (const float*)d_in[2];
  const float* Bm     = (const float*)d_in[3];
  const float* Cm     = (const float*)d_in[4];
  const float* Dv     = (const float*)d_in[5];
  float* y = (float*)d_out;

  float* Bu       = (float*)d_ws;                     // 4 MB
  float* xsl      = Bu + (long)ROWS * N;              // 4 MB
  float* F        = xsl + (long)ROWS * N;             // 64 KB
  float* carry_in = F + (long)BATCH * NCHUNK * N;     // 64 KB

  bu_gemm<<<ROWS / 64, 256, 0, stream>>>(u, Bm, Bu);
  local_scan<<<BATCH * NCHUNK, 64, 0, stream>>>(Bu, Lambda, log_dt, xsl, F);
  carry_scan<<<1, 256, 0, stream>>>(F, Lambda, log_dt, carry_in);
  y_gemm<<<(ROWS / 64) * (DM / 64), 256, 0, stream>>>(xsl, carry_in, Lambda, log_dt,
                                                      Cm, Dv, u, y);
}

// Round 4
// 96.980 us; speedup vs baseline: 6.3855x; 1.0385x over previous
//
#include <hip/hip_runtime.h>

// LiquidS4: y = (scan(a, u@B.T)) @ C.T + D*u
// shapes: u (4,4096,1024) f32; Lambda (64); log_dt (1); B (64,1024); C (1024,64); D (1024)

constexpr int BATCH  = 4;
constexpr int L      = 4096;
constexpr int DM     = 1024;
constexpr int N      = 64;
constexpr int ROWS   = BATCH * L;   // 16384
constexpr int CHUNK  = 64;          // timesteps per scan chunk
constexpr int NCHUNK = L / CHUNK;   // 64

// ---------------- Kernel 1: Bu_part[ks][row,n] = sum_{k in split} u[row,k]*B[n,k]
// 64 rows x 64 n tile, K-chunk 32, transposed LDS [k][m] (pad 68), reg double-buf.
// Grid (256, nsplit): blockIdx.y = k-split. 2 blocks/CU -> 8 waves/CU.
__global__ __launch_bounds__(256) void bu_gemm(const float* __restrict__ u,
                                               const float* __restrict__ Bm,
                                               float* __restrict__ BuP,
                                               int KR) {
  __shared__ __align__(16) float As[32][68];
  __shared__ __align__(16) float Bs[32][68];
  const int tid = threadIdx.x;
  const int tx = tid & 15;   // n-group
  const int ty = tid >> 4;   // row-group
  const int row0 = blockIdx.x * 64;
  const int kbase = blockIdx.y * KR;
  float* __restrict__ out = BuP + (long)blockIdx.y * ROWS * N;

  const int r0 = tid >> 3;          // rows 0..31
  const int q0 = tid & 7;
  const int r1 = r0 + 32;

  float acc[4][4] = {};
  float4 pa0, pa1, pb0, pb1;

  // prologue loads (chunk 0)
  pa0 = *reinterpret_cast<const float4*>(&u[(long)(row0 + r0) * DM + kbase + q0 * 4]);
  pa1 = *reinterpret_cast<const float4*>(&u[(long)(row0 + r1) * DM + kbase + q0 * 4]);
  pb0 = *reinterpret_cast<const float4*>(&Bm[(long)r0 * DM + kbase + q0 * 4]);
  pb1 = *reinterpret_cast<const float4*>(&Bm[(long)r1 * DM + kbase + q0 * 4]);

  const int NCH = KR / 32;
  for (int c = 0; c < NCH; ++c) {
    if (c) __syncthreads();          // LDS consumed by previous compute
    #pragma unroll
    for (int jj = 0; jj < 4; ++jj) {
      As[q0 * 4 + jj][r0] = (&pa0.x)[jj];
      As[q0 * 4 + jj][r1] = (&pa1.x)[jj];
      Bs[q0 * 4 + jj][r0] = (&pb0.x)[jj];
      Bs[q0 * 4 + jj][r1] = (&pb1.x)[jj];
    }
    __syncthreads();
    if (c + 1 < NCH) {               // issue next chunk's loads; latency hides under compute
      const int kn = kbase + (c + 1) * 32;
      pa0 = *reinterpret_cast<const float4*>(&u[(long)(row0 + r0) * DM + kn + q0 * 4]);
      pa1 = *reinterpret_cast<const float4*>(&u[(long)(row0 + r1) * DM + kn + q0 * 4]);
      pb0 = *reinterpret_cast<const float4*>(&Bm[(long)r0 * DM + kn + q0 * 4]);
      pb1 = *reinterpret_cast<const float4*>(&Bm[(long)r1 * DM + kn + q0 * 4]);
    }
    #pragma unroll
    for (int k = 0; k < 32; ++k) {
      const float4 av = *reinterpret_cast<const float4*>(&As[k][ty * 4]);
      const float4 bv = *reinterpret_cast<const float4*>(&Bs[k][tx * 4]);
      acc[0][0] = fmaf(av.x, bv.x, acc[0][0]);
      acc[0][1] = fmaf(av.x, bv.y, acc[0][1]);
      acc[0][2] = fmaf(av.x, bv.z, acc[0][2]);
      acc[0][3] = fmaf(av.x, bv.w, acc[0][3]);
      acc[1][0] = fmaf(av.y, bv.x, acc[1][0]);
      acc[1][1] = fmaf(av.y, bv.y, acc[1][1]);
      acc[1][2] = fmaf(av.y, bv.z, acc[1][2]);
      acc[1][3] = fmaf(av.y, bv.w, acc[1][3]);
      acc[2][0] = fmaf(av.z, bv.x, acc[2][0]);
      acc[2][1] = fmaf(av.z, bv.y, acc[2][1]);
      acc[2][2] = fmaf(av.z, bv.z, acc[2][2]);
      acc[2][3] = fmaf(av.z, bv.w, acc[2][3]);
      acc[3][0] = fmaf(av.w, bv.x, acc[3][0]);
      acc[3][1] = fmaf(av.w, bv.y, acc[3][1]);
      acc[3][2] = fmaf(av.w, bv.z, acc[3][2]);
      acc[3][3] = fmaf(av.w, bv.w, acc[3][3]);
    }
  }

  #pragma unroll
  for (int r = 0; r < 4; ++r) {
    const float4 v = make_float4(acc[r][0], acc[r][1], acc[r][2], acc[r][3]);
    *reinterpret_cast<float4*>(&out[(long)(row0 + ty * 4 + r) * N + tx * 4]) = v;
  }
}

// ---------------- Kernel 2: chunk-local scan (sums k-split partials) ----------
__global__ __launch_bounds__(64) void local_scan(const float* __restrict__ BuP,
                                                 const float* __restrict__ Lambda,
                                                 const float* __restrict__ log_dt,
                                                 float* __restrict__ xsl,
                                                 float* __restrict__ F,
                                                 int nsplit) {
  const int b = blockIdx.x >> 6;
  const int c = blockIdx.x & 63;
  const int n = threadIdx.x;
  const float dt = __expf(log_dt[0]);
  const float a  = __expf(-dt * __expf(Lambda[n]));

  const long base = ((long)b * L + (long)c * CHUNK) * N + n;
  float*       xp = xsl + base;

  float v[CHUNK];
  #pragma unroll
  for (int s = 0; s < CHUNK; ++s) v[s] = BuP[base + s * N];
  if (nsplit == 2) {
    const float* p2 = BuP + (long)ROWS * N;
    #pragma unroll
    for (int s = 0; s < CHUNK; ++s) v[s] += p2[base + s * N];
  }

  float x = 0.0f;
  #pragma unroll
  for (int s = 0; s < CHUNK; ++s) { x = fmaf(a, x, v[s]); v[s] = x; }

  #pragma unroll
  for (int s = 0; s < CHUNK; ++s) xp[s * N] = v[s];

  F[((b << 6) + c) * N + n] = x;
}

// ---------------- Kernel 3: carry scan + decay table ----------
// carry_in[b][c][n]; dec[t][n] = exp(w_n*(t+1)), t in 0..CHUNK-1.
__global__ __launch_bounds__(256) void carry_scan(const float* __restrict__ F,
                                                  const float* __restrict__ Lambda,
                                                  const float* __restrict__ log_dt,
                                                  float* __restrict__ carry_in,
                                                  float* __restrict__ dec) {
  const int t = threadIdx.x;
  const int b = t >> 6;
  const int n = t & 63;
  const float dt = __expf(log_dt[0]);
  const float w  = -dt * __expf(Lambda[n]);
  const float aS = __expf(w * (float)CHUNK);

  // decay table: thread group (t>>6) covers 16 timesteps
  #pragma unroll
  for (int i = 0; i < 16; ++i) {
    const int tt = (t >> 6) * 16 + i;
    dec[tt * N + n] = __expf(w * (float)(tt + 1));
  }

  float f[NCHUNK];
  #pragma unroll
  for (int c = 0; c < NCHUNK; ++c) f[c] = F[((b << 6) + c) * N + n];

  float P = 0.0f;
  #pragma unroll
  for (int c = 0; c < NCHUNK; ++c) {
    carry_in[((b << 6) + c) * N + n] = P;
    P = fmaf(aS, P, f[c]);
  }
}

// ---------------- Kernel 4: y = xs @ C.T + D*u -------------------------------
// 128 rows x 128 d tile, 8x8 acc, transposed LDS [n][m] pad 132 -> ds_read_b128.
// Carry fixup fused into Xs staging via dec table. Block spans 2 scan chunks.
__global__ __launch_bounds__(256) void y_gemm(const float* __restrict__ xsl,
                                              const float* __restrict__ carry_in,
                                              const float* __restrict__ dec,
                                              const float* __restrict__ Cm,
                                              const float* __restrict__ Dv,
                                              const float* __restrict__ u,
                                              float* __restrict__ y) {
  __shared__ __align__(16) float Xs[64][132];
  __shared__ __align__(16) float Cs[64][132];
  const int tid = threadIdx.x;
  const int tx = tid & 15;          // d-group (8 cols)
  const int ty = tid >> 4;          // row-group (8 rows)
  const int rt = blockIdx.x & 127;  // 128 row tiles
  const int dtile = blockIdx.x >> 7;
  const int row0 = rt * 128;
  const int d0   = dtile * 128;
  const int b    = row0 >> 12;          // / L
  const int c0   = (row0 & (L - 1)) >> 6;  // first scan chunk in tile

  // stage xs tile (transposed, with carry fixup): 128 rows x 64 n = 2048 float4
  #pragma unroll
  for (int i = 0; i < 8; ++i) {
    const int idx = tid + i * 256;
    const int r = idx >> 4, q = idx & 15;
    float4 v = *reinterpret_cast<const float4*>(&xsl[(long)(row0 + r) * N + q * 4]);
    const float4 dv = *reinterpret_cast<const float4*>(&dec[(r & 63) * N + q * 4]);
    const float4 cv = *reinterpret_cast<const float4*>(
        &carry_in[((b << 6) + c0 + (r >> 6)) * N + q * 4]);
    v.x = fmaf(dv.x, cv.x, v.x);
    v.y = fmaf(dv.y, cv.y, v.y);
    v.z = fmaf(dv.z, cv.z, v.z);
    v.w = fmaf(dv.w, cv.w, v.w);
    Xs[q * 4 + 0][r] = v.x; Xs[q * 4 + 1][r] = v.y;
    Xs[q * 4 + 2][r] = v.z; Xs[q * 4 + 3][r] = v.w;
  }
  // stage C tile (transposed): 128 d x 64 n
  #pragma unroll
  for (int i = 0; i < 8; ++i) {
    const int idx = tid + i * 256;
    const int r = idx >> 4, q = idx & 15;
    const float4 v = *reinterpret_cast<const float4*>(&Cm[(long)(d0 + r) * N + q * 4]);
    Cs[q * 4 + 0][r] = v.x; Cs[q * 4 + 1][r] = v.y;
    Cs[q * 4 + 2][r] = v.z; Cs[q * 4 + 3][r] = v.w;
  }
  __syncthreads();

  float acc[8][8] = {};
  #pragma unroll 4
  for (int k = 0; k < 64; ++k) {
    const float4 a0 = *reinterpret_cast<const float4*>(&Xs[k][ty * 8]);
    const float4 a1 = *reinterpret_cast<const float4*>(&Xs[k][ty * 8 + 4]);
    const float4 b0 = *reinterpret_cast<const float4*>(&Cs[k][tx * 8]);
    const float4 b1 = *reinterpret_cast<const float4*>(&Cs[k][tx * 8 + 4]);
    const float av[8] = {a0.x, a0.y, a0.z, a0.w, a1.x, a1.y, a1.z, a1.w};
    const float bv[8] = {b0.x, b0.y, b0.z, b0.w, b1.x, b1.y, b1.z, b1.w};
    #pragma unroll
    for (int r = 0; r < 8; ++r)
      #pragma unroll
      for (int cc = 0; cc < 8; ++cc)
        acc[r][cc] = fmaf(av[r], bv[cc], acc[r][cc]);
  }

  // epilogue: + D*u
  const float4 dd0 = *reinterpret_cast<const float4*>(&Dv[d0 + tx * 8]);
  const float4 dd1 = *reinterpret_cast<const float4*>(&Dv[d0 + tx * 8 + 4]);
  #pragma unroll
  for (int r = 0; r < 8; ++r) {
    const long row = row0 + ty * 8 + r;
    const float4 u0 = *reinterpret_cast<const float4*>(&u[row * DM + d0 + tx * 8]);
    const float4 u1 = *reinterpret_cast<const float4*>(&u[row * DM + d0 + tx * 8 + 4]);
    float4 o0, o1;
    o0.x = fmaf(dd0.x, u0.x, acc[r][0]);
    o0.y = fmaf(dd0.y, u0.y, acc[r][1]);
    o0.z = fmaf(dd0.z, u0.z, acc[r][2]);
    o0.w = fmaf(dd0.w, u0.w, acc[r][3]);
    o1.x = fmaf(dd1.x, u1.x, acc[r][4]);
    o1.y = fmaf(dd1.y, u1.y, acc[r][5]);
    o1.z = fmaf(dd1.z, u1.z, acc[r][6]);
    o1.w = fmaf(dd1.w, u1.w, acc[r][7]);
    *reinterpret_cast<float4*>(&y[row * DM + d0 + tx * 8]) = o0;
    *reinterpret_cast<float4*>(&y[row * DM + d0 + tx * 8 + 4]) = o1;
  }
}

extern "C" void kernel_launch(void* const* d_in, const int* in_sizes, int n_in,
                              void* d_out, int out_size, void* d_ws, size_t ws_size,
                              hipStream_t stream) {
  const float* u      = (const float*)d_in[0];
  const float* Lambda = (const float*)d_in[1];
  const float* log_dt = (const float*)d_in[2];
  const float* Bm     = (const float*)d_in[3];
  const float* Cm     = (const float*)d_in[4];
  const float* Dv     = (const float*)d_in[5];
  float* y = (float*)d_out;

  const size_t planeB = (size_t)ROWS * N;                  // 1M floats = 4 MB
  const size_t need2  = (3 * planeB + 2 * BATCH * NCHUNK * N + CHUNK * N) * 4;
  const int nsplit = (ws_size >= need2) ? 2 : 1;

  float* BuP      = (float*)d_ws;                          // nsplit * 4 MB
  float* xsl      = BuP + (size_t)nsplit * planeB;         // 4 MB
  float* F        = xsl + planeB;                          // 64 KB
  float* carry_in = F + (size_t)BATCH * NCHUNK * N;        // 64 KB
  float* dec      = carry_in + (size_t)BATCH * NCHUNK * N; // 16 KB

  bu_gemm<<<dim3(ROWS / 64, nsplit), 256, 0, stream>>>(u, Bm, BuP, DM / nsplit);
  local_scan<<<BATCH * NCHUNK, 64, 0, stream>>>(BuP, Lambda, log_dt, xsl, F, nsplit);
  carry_scan<<<1, 256, 0, stream>>>(F, Lambda, log_dt, carry_in, dec);
  y_gemm<<<(ROWS / 128) * (DM / 128), 256, 0, stream>>>(xsl, carry_in, dec,
                                                        Cm, Dv, u, y);
}

// Round 5
// 41.706 us; speedup vs baseline: 14.8483x; 2.3253x over previous
//
#include <hip/hip_runtime.h>

// LiquidS4: y = (scan(a, u@B.T)) @ C.T + D*u
// u (4,4096,1024) f32; Lambda (64); log_dt (1); B (64,1024); C (1024,64); D (1024)

constexpr int BATCH  = 4;
constexpr int L      = 4096;
constexpr int DM     = 1024;
constexpr int N      = 64;
constexpr int ROWS   = BATCH * L;    // 16384
constexpr int CHUNK  = 32;           // timesteps per scan chunk
constexpr int NCHUNK = L / CHUNK;    // 128

typedef __attribute__((ext_vector_type(8))) short     bf16x8;
typedef __attribute__((ext_vector_type(4))) float     f32x4;

__device__ __forceinline__ unsigned short f2bf(float f) {
  unsigned int u = __float_as_uint(f);
  u += 0x7FFFu + ((u >> 16) & 1u);          // round-to-nearest-even
  return (unsigned short)(u >> 16);
}

// ---------------- Kernel 1: Bu_part = u[:, ksplit] @ B[:, ksplit].T (bf16 MFMA)
// Tile 64 rows x 64 n, K-chunk 64, LDS [m][k] bf16 pad-72 (144B rows: balanced
// banks for ds_read_b128 fragments), LDS double-buffer + reg prefetch.
__global__ __launch_bounds__(256) void bu_gemm(const float* __restrict__ u,
                                               const float* __restrict__ Bm,
                                               float* __restrict__ BuP,
                                               int KR) {
  __shared__ __align__(16) unsigned short As[2][64][72];
  __shared__ __align__(16) unsigned short Bs[2][64][72];
  const int tid  = threadIdx.x;
  const int lane = tid & 63;
  const int wv   = tid >> 6;           // wave 0..3 -> rows wv*16..+16
  const int l15  = lane & 15;
  const int g    = lane >> 4;          // k-group 0..3
  const int row0 = blockIdx.x * 64;
  const int kbase = blockIdx.y * KR;
  float* __restrict__ out = BuP + (long)blockIdx.y * ROWS * N;

  const int sr = tid >> 4;             // staging row 0..15 (+i*16)
  const int sq = tid & 15;             // staging k-quad (4 floats)

  f32x4 acc[4] = {};
  float4 pa[4], pb[4];

  const int NCH = KR / 64;
  // prologue: chunk 0 -> regs
  {
    const int kb = kbase;
    #pragma unroll
    for (int i = 0; i < 4; ++i) {
      const int r = sr + i * 16;
      pa[i] = *reinterpret_cast<const float4*>(&u[(long)(row0 + r) * DM + kb + sq * 4]);
      pb[i] = *reinterpret_cast<const float4*>(&Bm[(long)r * DM + kb + sq * 4]);
    }
  }

  for (int c = 0; c < NCH; ++c) {
    const int buf = c & 1;
    if (c) __syncthreads();            // prev compute done reading buf
    #pragma unroll
    for (int i = 0; i < 4; ++i) {
      const int r = sr + i * 16;
      ushort4 ha = make_ushort4(f2bf(pa[i].x), f2bf(pa[i].y), f2bf(pa[i].z), f2bf(pa[i].w));
      ushort4 hb = make_ushort4(f2bf(pb[i].x), f2bf(pb[i].y), f2bf(pb[i].z), f2bf(pb[i].w));
      *reinterpret_cast<ushort4*>(&As[buf][r][sq * 4]) = ha;
      *reinterpret_cast<ushort4*>(&Bs[buf][r][sq * 4]) = hb;
    }
    __syncthreads();
    if (c + 1 < NCH) {                 // prefetch next chunk (hides under MFMA)
      const int kb = kbase + (c + 1) * 64;
      #pragma unroll
      for (int i = 0; i < 4; ++i) {
        const int r = sr + i * 16;
        pa[i] = *reinterpret_cast<const float4*>(&u[(long)(row0 + r) * DM + kb + sq * 4]);
        pb[i] = *reinterpret_cast<const float4*>(&Bm[(long)r * DM + kb + sq * 4]);
      }
    }
    #pragma unroll
    for (int ks = 0; ks < 2; ++ks) {
      const bf16x8 af = *reinterpret_cast<const bf16x8*>(
          &As[buf][wv * 16 + l15][ks * 32 + g * 8]);
      #pragma unroll
      for (int t = 0; t < 4; ++t) {
        const bf16x8 bfr = *reinterpret_cast<const bf16x8*>(
            &Bs[buf][t * 16 + l15][ks * 32 + g * 8]);
        acc[t] = __builtin_amdgcn_mfma_f32_16x16x32_bf16(af, bfr, acc[t], 0, 0, 0);
      }
    }
  }

  // D-frag: col = lane&15 (n), row = (lane>>4)*4 + reg
  const int orow = row0 + wv * 16 + g * 4;
  #pragma unroll
  for (int t = 0; t < 4; ++t)
    #pragma unroll
    for (int r = 0; r < 4; ++r)
      out[(long)(orow + r) * N + t * 16 + l15] = acc[t][r];
}

// ---------------- Kernel 2: chunk finals F (+ C -> bf16 convert) --------------
__global__ __launch_bounds__(256) void f_scan(const float* __restrict__ BuP,
                                              const float* __restrict__ Lambda,
                                              const float* __restrict__ log_dt,
                                              float* __restrict__ F,
                                              const float* __restrict__ Cm,
                                              unsigned short* __restrict__ Cb,
                                              int nsplit) {
  // C convert: 16384 float4 over 128 blocks x 128 threads
  if (threadIdx.x < 128) {
    const int i = blockIdx.x * 128 + threadIdx.x;
    const float4 v = *reinterpret_cast<const float4*>(&Cm[(long)i * 4]);
    *reinterpret_cast<ushort4*>(&Cb[(long)i * 4]) =
        make_ushort4(f2bf(v.x), f2bf(v.y), f2bf(v.z), f2bf(v.w));
  }

  const int pair = blockIdx.x * 4 + (threadIdx.x >> 6);   // b*NCHUNK + c
  const int b = pair >> 7, c = pair & 127;
  const int n = threadIdx.x & 63;
  const long base = ((long)b * L + (long)c * CHUNK) * N + n;

  float v[CHUNK];
  #pragma unroll
  for (int s = 0; s < CHUNK; ++s) v[s] = BuP[base + s * N];
  if (nsplit == 2) {
    const float* p2 = BuP + (long)ROWS * N;
    #pragma unroll
    for (int s = 0; s < CHUNK; ++s) v[s] += p2[base + s * N];
  }

  const float dt = __expf(log_dt[0]);
  const float a  = __expf(-dt * __expf(Lambda[n]));
  float x = 0.0f;
  #pragma unroll
  for (int s = 0; s < CHUNK; ++s) x = fmaf(a, x, v[s]);
  F[pair * N + n] = x;
}

// ---------------- Kernel 3: carry over chunk finals ---------------------------
__global__ __launch_bounds__(256) void carry_scan(const float* __restrict__ F,
                                                  const float* __restrict__ Lambda,
                                                  const float* __restrict__ log_dt,
                                                  float* __restrict__ carry) {
  const int t = threadIdx.x;
  const int b = t >> 6;
  const int n = t & 63;
  const float dt = __expf(log_dt[0]);
  const float w  = -dt * __expf(Lambda[n]);
  const float aS = __expf(w * (float)CHUNK);

  float f[NCHUNK];
  #pragma unroll
  for (int c = 0; c < NCHUNK; ++c) f[c] = F[(b * NCHUNK + c) * N + n];

  float P = 0.0f;
  #pragma unroll
  for (int c = 0; c < NCHUNK; ++c) {
    carry[(b * NCHUNK + c) * N + n] = P;
    P = fmaf(aS, P, f[c]);
  }
}

// ---------------- Kernel 4: re-scan with exact carry, write xs in bf16 --------
__global__ __launch_bounds__(256) void xs_scan(const float* __restrict__ BuP,
                                               const float* __restrict__ carry,
                                               const float* __restrict__ Lambda,
                                               const float* __restrict__ log_dt,
                                               unsigned short* __restrict__ xsb,
                                               int nsplit) {
  const int pair = blockIdx.x * 4 + (threadIdx.x >> 6);
  const int b = pair >> 7, c = pair & 127;
  const int n = threadIdx.x & 63;
  const long base = ((long)b * L + (long)c * CHUNK) * N + n;

  float v[CHUNK];
  #pragma unroll
  for (int s = 0; s < CHUNK; ++s) v[s] = BuP[base + s * N];
  if (nsplit == 2) {
    const float* p2 = BuP + (long)ROWS * N;
    #pragma unroll
    for (int s = 0; s < CHUNK; ++s) v[s] += p2[base + s * N];
  }

  const float dt = __expf(log_dt[0]);
  const float a  = __expf(-dt * __expf(Lambda[n]));
  float x = carry[pair * N + n];
  #pragma unroll
  for (int s = 0; s < CHUNK; ++s) {
    x = fmaf(a, x, v[s]);
    xsb[base + s * N] = f2bf(x);
  }
}

// ---------------- Kernel 5: y = xs @ C.T (+ D*u, skipped per-lane if D==0) ----
// Tile 64 rows x 128 d, bf16 MFMA, K=64 (2 k-steps). LDS 28 KB -> 5 blocks/CU.
__global__ __launch_bounds__(256) void y_gemm(const unsigned short* __restrict__ xsb,
                                              const unsigned short* __restrict__ Cb,
                                              const float* __restrict__ Dv,
                                              const float* __restrict__ u,
                                              float* __restrict__ y) {
  __shared__ __align__(16) unsigned short Xs[64][72];
  __shared__ __align__(16) unsigned short Cs[128][72];
  __shared__ float Dsh[128];
  const int tid  = threadIdx.x;
  const int lane = tid & 63;
  const int wv   = tid >> 6;
  const int l15  = lane & 15;
  const int g    = lane >> 4;
  const int row0 = (blockIdx.x & 255) * 64;
  const int d0   = (blockIdx.x >> 8) * 128;

  // stage Xs: 64 rows x 64 n bf16 = 512 x 16B
  #pragma unroll
  for (int i = 0; i < 2; ++i) {
    const int idx = tid + i * 256;
    const int r = idx >> 3, q = idx & 7;
    const uint4 v = *reinterpret_cast<const uint4*>(&xsb[(long)(row0 + r) * N + q * 8]);
    *reinterpret_cast<uint4*>(&Xs[r][q * 8]) = v;
  }
  // stage Cs: 128 d x 64 n bf16 = 1024 x 16B
  #pragma unroll
  for (int i = 0; i < 4; ++i) {
    const int idx = tid + i * 256;
    const int r = idx >> 3, q = idx & 7;
    const uint4 v = *reinterpret_cast<const uint4*>(&Cb[(long)(d0 + r) * N + q * 8]);
    *reinterpret_cast<uint4*>(&Cs[r][q * 8]) = v;
  }
  if (tid < 128) Dsh[tid] = Dv[d0 + tid];
  __syncthreads();

  bf16x8 af[2];
  #pragma unroll
  for (int ks = 0; ks < 2; ++ks)
    af[ks] = *reinterpret_cast<const bf16x8*>(&Xs[wv * 16 + l15][ks * 32 + g * 8]);

  f32x4 acc[8] = {};
  #pragma unroll
  for (int t = 0; t < 8; ++t) {
    #pragma unroll
    for (int ks = 0; ks < 2; ++ks) {
      const bf16x8 bfr = *reinterpret_cast<const bf16x8*>(
          &Cs[t * 16 + l15][ks * 32 + g * 8]);
      acc[t] = __builtin_amdgcn_mfma_f32_16x16x32_bf16(af[ks], bfr, acc[t], 0, 0, 0);
    }
  }

  // epilogue: col = d0 + t*16 + l15, rows orow..+3. D==0 lanes skip u entirely.
  const int orow = row0 + wv * 16 + g * 4;
  #pragma unroll
  for (int t = 0; t < 8; ++t) {
    const int ocol = d0 + t * 16 + l15;
    const float dD = Dsh[t * 16 + l15];
    if (dD != 0.0f) {
      #pragma unroll
      for (int r = 0; r < 4; ++r) {
        const float uu = u[(long)(orow + r) * DM + ocol];
        y[(long)(orow + r) * DM + ocol] = fmaf(dD, uu, acc[t][r]);
      }
    } else {
      #pragma unroll
      for (int r = 0; r < 4; ++r)
        y[(long)(orow + r) * DM + ocol] = acc[t][r];
    }
  }
}

extern "C" void kernel_launch(void* const* d_in, const int* in_sizes, int n_in,
                              void* d_out, int out_size, void* d_ws, size_t ws_size,
                              hipStream_t stream) {
  const float* u      = (const float*)d_in[0];
  const float* Lambda = (const float*)d_in[1];
  const float* log_dt = (const float*)d_in[2];
  const float* Bm     = (const float*)d_in[3];
  const float* Cm     = (const float*)d_in[4];
  const float* Dv     = (const float*)d_in[5];
  float* y = (float*)d_out;

  const size_t planeB = (size_t)ROWS * N;   // 1M floats
  // layout: BuP (nsplit planes f32) | F | carry (f32) | xsb (bf16) | Cb (bf16)
  const size_t smallf = (size_t)BATCH * NCHUNK * N;  // 32K floats
  const size_t need2  = (2 * planeB + 2 * smallf) * 4 + planeB * 2 + (size_t)DM * N * 2;
  const int nsplit = (ws_size >= need2) ? 2 : 1;

  float* BuP   = (float*)d_ws;
  float* F     = BuP + (size_t)nsplit * planeB;
  float* carry = F + smallf;
  unsigned short* xsb = (unsigned short*)(carry + smallf);
  unsigned short* Cb  = xsb + planeB;

  bu_gemm<<<dim3(ROWS / 64, nsplit), 256, 0, stream>>>(u, Bm, BuP, DM / nsplit);
  f_scan<<<BATCH * NCHUNK / 4, 256, 0, stream>>>(BuP, Lambda, log_dt, F, Cm, Cb, nsplit);
  carry_scan<<<1, 256, 0, stream>>>(F, Lambda, log_dt, carry);
  xs_scan<<<BATCH * NCHUNK / 4, 256, 0, stream>>>(BuP, carry, Lambda, log_dt, xsb, nsplit);
  y_gemm<<<(ROWS / 64) * (DM / 128), 256, 0, stream>>>(xsb, Cb, Dv, u, y);
}

// Round 6
// 40.256 us; speedup vs baseline: 15.3831x; 1.0360x over previous
//
#include <hip/hip_runtime.h>

// LiquidS4: y = (scan(a, u@B.T)) @ C.T + D*u
// u (4,4096,1024) f32; Lambda (64); log_dt (1); B (64,1024); C (1024,64); D (1024)

constexpr int BATCH  = 4;
constexpr int L      = 4096;
constexpr int DM     = 1024;
constexpr int N      = 64;
constexpr int ROWS   = BATCH * L;    // 16384
constexpr int CHUNK  = 32;           // timesteps per scan chunk
constexpr int NCHUNK = L / CHUNK;    // 128

typedef __attribute__((ext_vector_type(8))) short     bf16x8;
typedef __attribute__((ext_vector_type(4))) float     f32x4;

__device__ __forceinline__ unsigned short f2bf(float f) {
  unsigned int u = __float_as_uint(f);
  u += 0x7FFFu + ((u >> 16) & 1u);          // round-to-nearest-even
  return (unsigned short)(u >> 16);
}

// ---------------- Kernel 1: Bu_part = u[:, ksplit] @ B[:, ksplit].T (bf16 MFMA)
// Tile 64 rows x 64 n, K-chunk 64, LDS [m][k] bf16 pad-72, dbuf + reg prefetch.
__global__ __launch_bounds__(256) void bu_gemm(const float* __restrict__ u,
                                               const float* __restrict__ Bm,
                                               float* __restrict__ BuP,
                                               int KR) {
  __shared__ __align__(16) unsigned short As[2][64][72];
  __shared__ __align__(16) unsigned short Bs[2][64][72];
  const int tid  = threadIdx.x;
  const int lane = tid & 63;
  const int wv   = tid >> 6;           // wave 0..3 -> rows wv*16..+16
  const int l15  = lane & 15;
  const int g    = lane >> 4;          // k-group 0..3
  const int row0 = blockIdx.x * 64;
  const int kbase = blockIdx.y * KR;
  float* __restrict__ out = BuP + (long)blockIdx.y * ROWS * N;

  const int sr = tid >> 4;             // staging row 0..15 (+i*16)
  const int sq = tid & 15;             // staging k-quad (4 floats)

  f32x4 acc[4] = {};
  float4 pa[4], pb[4];

  const int NCH = KR / 64;
  {
    const int kb = kbase;
    #pragma unroll
    for (int i = 0; i < 4; ++i) {
      const int r = sr + i * 16;
      pa[i] = *reinterpret_cast<const float4*>(&u[(long)(row0 + r) * DM + kb + sq * 4]);
      pb[i] = *reinterpret_cast<const float4*>(&Bm[(long)r * DM + kb + sq * 4]);
    }
  }

  for (int c = 0; c < NCH; ++c) {
    const int buf = c & 1;
    if (c) __syncthreads();
    #pragma unroll
    for (int i = 0; i < 4; ++i) {
      const int r = sr + i * 16;
      ushort4 ha = make_ushort4(f2bf(pa[i].x), f2bf(pa[i].y), f2bf(pa[i].z), f2bf(pa[i].w));
      ushort4 hb = make_ushort4(f2bf(pb[i].x), f2bf(pb[i].y), f2bf(pb[i].z), f2bf(pb[i].w));
      *reinterpret_cast<ushort4*>(&As[buf][r][sq * 4]) = ha;
      *reinterpret_cast<ushort4*>(&Bs[buf][r][sq * 4]) = hb;
    }
    __syncthreads();
    if (c + 1 < NCH) {
      const int kb = kbase + (c + 1) * 64;
      #pragma unroll
      for (int i = 0; i < 4; ++i) {
        const int r = sr + i * 16;
        pa[i] = *reinterpret_cast<const float4*>(&u[(long)(row0 + r) * DM + kb + sq * 4]);
        pb[i] = *reinterpret_cast<const float4*>(&Bm[(long)r * DM + kb + sq * 4]);
      }
    }
    #pragma unroll
    for (int ks = 0; ks < 2; ++ks) {
      const bf16x8 af = *reinterpret_cast<const bf16x8*>(
          &As[buf][wv * 16 + l15][ks * 32 + g * 8]);
      #pragma unroll
      for (int t = 0; t < 4; ++t) {
        const bf16x8 bfr = *reinterpret_cast<const bf16x8*>(
            &Bs[buf][t * 16 + l15][ks * 32 + g * 8]);
        acc[t] = __builtin_amdgcn_mfma_f32_16x16x32_bf16(af, bfr, acc[t], 0, 0, 0);
      }
    }
  }

  // D-frag: col = lane&15 (n), row = (lane>>4)*4 + reg
  const int orow = row0 + wv * 16 + g * 4;
  #pragma unroll
  for (int t = 0; t < 4; ++t)
    #pragma unroll
    for (int r = 0; r < 4; ++r)
      out[(long)(orow + r) * N + t * 16 + l15] = acc[t][r];
}

// ---------------- Kernel 2: chunk finals F (+ C -> bf16 convert) --------------
__global__ __launch_bounds__(256) void f_scan(const float* __restrict__ BuP,
                                              const float* __restrict__ Lambda,
                                              const float* __restrict__ log_dt,
                                              float* __restrict__ F,
                                              const float* __restrict__ Cm,
                                              unsigned short* __restrict__ Cb,
                                              int nsplit) {
  if (threadIdx.x < 128) {
    const int i = blockIdx.x * 128 + threadIdx.x;
    const float4 v = *reinterpret_cast<const float4*>(&Cm[(long)i * 4]);
    *reinterpret_cast<ushort4*>(&Cb[(long)i * 4]) =
        make_ushort4(f2bf(v.x), f2bf(v.y), f2bf(v.z), f2bf(v.w));
  }

  const int pair = blockIdx.x * 4 + (threadIdx.x >> 6);
  const int b = pair >> 7, c = pair & 127;
  const int n = threadIdx.x & 63;
  const long base = ((long)b * L + (long)c * CHUNK) * N + n;

  float v[CHUNK];
  #pragma unroll
  for (int s = 0; s < CHUNK; ++s) v[s] = BuP[base + s * N];
  if (nsplit == 2) {
    const float* p2 = BuP + (long)ROWS * N;
    #pragma unroll
    for (int s = 0; s < CHUNK; ++s) v[s] += p2[base + s * N];
  }

  const float dt = __expf(log_dt[0]);
  const float a  = __expf(-dt * __expf(Lambda[n]));
  float x = 0.0f;
  #pragma unroll
  for (int s = 0; s < CHUNK; ++s) x = fmaf(a, x, v[s]);
  F[pair * N + n] = x;
}

// ---------------- Kernel 3: carry over chunk finals ---------------------------
__global__ __launch_bounds__(256) void carry_scan(const float* __restrict__ F,
                                                  const float* __restrict__ Lambda,
                                                  const float* __restrict__ log_dt,
                                                  float* __restrict__ carry) {
  const int t = threadIdx.x;
  const int b = t >> 6;
  const int n = t & 63;
  const float dt = __expf(log_dt[0]);
  const float w  = -dt * __expf(Lambda[n]);
  const float aS = __expf(w * (float)CHUNK);

  float f[NCHUNK];
  #pragma unroll
  for (int c = 0; c < NCHUNK; ++c) f[c] = F[(b * NCHUNK + c) * N + n];

  float P = 0.0f;
  #pragma unroll
  for (int c = 0; c < NCHUNK; ++c) {
    carry[(b * NCHUNK + c) * N + n] = P;
    P = fmaf(aS, P, f[c]);
  }
}

// ---------------- Kernel 4: re-scan with exact carry, write xs in bf16 --------
__global__ __launch_bounds__(256) void xs_scan(const float* __restrict__ BuP,
                                               const float* __restrict__ carry,
                                               const float* __restrict__ Lambda,
                                               const float* __restrict__ log_dt,
                                               unsigned short* __restrict__ xsb,
                                               int nsplit) {
  const int pair = blockIdx.x * 4 + (threadIdx.x >> 6);
  const int b = pair >> 7, c = pair & 127;
  const int n = threadIdx.x & 63;
  const long base = ((long)b * L + (long)c * CHUNK) * N + n;

  float v[CHUNK];
  #pragma unroll
  for (int s = 0; s < CHUNK; ++s) v[s] = BuP[base + s * N];
  if (nsplit == 2) {
    const float* p2 = BuP + (long)ROWS * N;
    #pragma unroll
    for (int s = 0; s < CHUNK; ++s) v[s] += p2[base + s * N];
  }

  const float dt = __expf(log_dt[0]);
  const float a  = __expf(-dt * __expf(Lambda[n]));
  float x = carry[pair * N + n];
  #pragma unroll
  for (int s = 0; s < CHUNK; ++s) {
    x = fmaf(a, x, v[s]);
    xsb[base + s * N] = f2bf(x);
  }
}

// ---------------- Kernel 5: y = xs @ C.T (+ D*u per-float4 if D!=0) -----------
// Tile 64 rows x 128 d, bf16 MFMA, K=64. LDS-transpose epilogue -> float4 stores.
// Staging LDS and transpose tile are union'd (34 KB -> 4 blocks/CU).
__global__ __launch_bounds__(256) void y_gemm(const unsigned short* __restrict__ xsb,
                                              const unsigned short* __restrict__ Cb,
                                              const float* __restrict__ Dv,
                                              const float* __restrict__ u,
                                              float* __restrict__ y) {
  __shared__ __align__(16) char smem[64 * 132 * 4];   // 33792 B union
  unsigned short (*Xs)[72] = reinterpret_cast<unsigned short (*)[72]>(smem);            // 9216 B
  unsigned short (*Cs)[72] = reinterpret_cast<unsigned short (*)[72]>(smem + 9216);     // 18432 B
  float (*T)[132] = reinterpret_cast<float (*)[132]>(smem);                             // 33792 B
  __shared__ float Dsh[128];

  const int tid  = threadIdx.x;
  const int lane = tid & 63;
  const int wv   = tid >> 6;
  const int l15  = lane & 15;
  const int g    = lane >> 4;
  const int row0 = (blockIdx.x & 255) * 64;
  const int d0   = (blockIdx.x >> 8) * 128;

  // stage Xs: 64 rows x 64 n bf16
  #pragma unroll
  for (int i = 0; i < 2; ++i) {
    const int idx = tid + i * 256;
    const int r = idx >> 3, q = idx & 7;
    const uint4 v = *reinterpret_cast<const uint4*>(&xsb[(long)(row0 + r) * N + q * 8]);
    *reinterpret_cast<uint4*>(&Xs[r][q * 8]) = v;
  }
  // stage Cs: 128 d x 64 n bf16
  #pragma unroll
  for (int i = 0; i < 4; ++i) {
    const int idx = tid + i * 256;
    const int r = idx >> 3, q = idx & 7;
    const uint4 v = *reinterpret_cast<const uint4*>(&Cb[(long)(d0 + r) * N + q * 8]);
    *reinterpret_cast<uint4*>(&Cs[r][q * 8]) = v;
  }
  if (tid < 128) Dsh[tid] = Dv[d0 + tid];
  __syncthreads();

  bf16x8 af[2];
  #pragma unroll
  for (int ks = 0; ks < 2; ++ks)
    af[ks] = *reinterpret_cast<const bf16x8*>(&Xs[wv * 16 + l15][ks * 32 + g * 8]);

  f32x4 acc[8] = {};
  #pragma unroll
  for (int t = 0; t < 8; ++t) {
    #pragma unroll
    for (int ks = 0; ks < 2; ++ks) {
      const bf16x8 bfr = *reinterpret_cast<const bf16x8*>(
          &Cs[t * 16 + l15][ks * 32 + g * 8]);
      acc[t] = __builtin_amdgcn_mfma_f32_16x16x32_bf16(af[ks], bfr, acc[t], 0, 0, 0);
    }
  }

  // transpose via LDS: acc lane layout (col = t*16+l15, rows wv*16+g*4..+3)
  __syncthreads();   // staging fully consumed; safe to overwrite union
  #pragma unroll
  for (int t = 0; t < 8; ++t)
    #pragma unroll
    for (int r = 0; r < 4; ++r)
      T[wv * 16 + g * 4 + r][t * 16 + l15] = acc[t][r];
  __syncthreads();

  // coalesced float4 stores: 2048 quads over 256 threads
  #pragma unroll
  for (int i = 0; i < 8; ++i) {
    const int id = tid + i * 256;
    const int r = id >> 5;        // 0..63
    const int q = id & 31;        // col-quad 0..31
    float4 v = *reinterpret_cast<const float4*>(&T[r][q * 4]);
    const float4 dd = *reinterpret_cast<const float4*>(&Dsh[q * 4]);
    if (dd.x != 0.0f || dd.y != 0.0f || dd.z != 0.0f || dd.w != 0.0f) {
      const float4 uu = *reinterpret_cast<const float4*>(
          &u[(long)(row0 + r) * DM + d0 + q * 4]);
      v.x = fmaf(dd.x, uu.x, v.x);
      v.y = fmaf(dd.y, uu.y, v.y);
      v.z = fmaf(dd.z, uu.z, v.z);
      v.w = fmaf(dd.w, uu.w, v.w);
    }
    *reinterpret_cast<float4*>(&y[(long)(row0 + r) * DM + d0 + q * 4]) = v;
  }
}

extern "C" void kernel_launch(void* const* d_in, const int* in_sizes, int n_in,
                              void* d_out, int out_size, void* d_ws, size_t ws_size,
                              hipStream_t stream) {
  const float* u      = (const float*)d_in[0];
  const float* Lambda = (const float*)d_in[1];
  const float* log_dt = (const float*)d_in[2];
  const float* Bm     = (const float*)d_in[3];
  const float* Cm     = (const float*)d_in[4];
  const float* Dv     = (const float*)d_in[5];
  float* y = (float*)d_out;

  const size_t planeB = (size_t)ROWS * N;
  const size_t smallf = (size_t)BATCH * NCHUNK * N;
  const size_t need2  = (2 * planeB + 2 * smallf) * 4 + planeB * 2 + (size_t)DM * N * 2;
  const int nsplit = (ws_size >= need2) ? 2 : 1;

  float* BuP   = (float*)d_ws;
  float* F     = BuP + (size_t)nsplit * planeB;
  float* carry = F + smallf;
  unsigned short* xsb = (unsigned short*)(carry + smallf);
  unsigned short* Cb  = xsb + planeB;

  bu_gemm<<<dim3(ROWS / 64, nsplit), 256, 0, stream>>>(u, Bm, BuP, DM / nsplit);
  f_scan<<<BATCH * NCHUNK / 4, 256, 0, stream>>>(BuP, Lambda, log_dt, F, Cm, Cb, nsplit);
  carry_scan<<<1, 256, 0, stream>>>(F, Lambda, log_dt, carry);
  xs_scan<<<BATCH * NCHUNK / 4, 256, 0, stream>>>(BuP, carry, Lambda, log_dt, xsb, nsplit);
  y_gemm<<<(ROWS / 64) * (DM / 128), 256, 0, stream>>>(xsb, Cb, Dv, u, y);
}

// Round 7
// 38.542 us; speedup vs baseline: 16.0671x; 1.0445x over previous
//
#include <hip/hip_runtime.h>

// LiquidS4: y = (scan(a, u@B.T)) @ C.T + D*u
// u (4,4096,1024) f32; Lambda (64); log_dt (1); B (64,1024); C (1024,64); D (1024)
// 3-kernel fused pipeline: bu_scan (GEMM+local scan) -> carry_scan -> y_gemm.

constexpr int BATCH  = 4;
constexpr int L      = 4096;
constexpr int DM     = 1024;
constexpr int N      = 64;
constexpr int ROWS   = BATCH * L;    // 16384
constexpr int CHUNK  = 64;           // = bu_scan row-tile -> one chunk per block
constexpr int NCHUNK = L / CHUNK;    // 64

typedef __attribute__((ext_vector_type(8))) short     bf16x8;
typedef __attribute__((ext_vector_type(4))) float     f32x4;

__device__ __forceinline__ unsigned short f2bf(float f) {
  unsigned int u = __float_as_uint(f);
  u += 0x7FFFu + ((u >> 16) & 1u);          // round-to-nearest-even
  return (unsigned short)(u >> 16);
}

// ---------------- Kernel 1: Bu = u @ B.T (bf16 MFMA) + chunk-local scan -------
// Block = 64 rows = 64 consecutive timesteps of one batch = one scan chunk.
// Bu never goes to HBM: acc -> LDS transpose -> wave-0 register scan ->
// xs-local f32 + chunk-final F.
__global__ __launch_bounds__(256) void bu_scan(const float* __restrict__ u,
                                               const float* __restrict__ Bm,
                                               const float* __restrict__ Lambda,
                                               const float* __restrict__ log_dt,
                                               float* __restrict__ xs,
                                               float* __restrict__ F) {
  __shared__ __align__(16) char smem[36864];
  typedef unsigned short AsT[64][72];
  AsT* As = reinterpret_cast<AsT*>(smem);              // [2][64][72] = 18432 B
  AsT* Bs = reinterpret_cast<AsT*>(smem + 18432);      // [2][64][72] = 18432 B
  float (*T)[68] = reinterpret_cast<float (*)[68]>(smem);  // 17408 B, unions As

  const int tid  = threadIdx.x;
  const int lane = tid & 63;
  const int wv   = tid >> 6;           // wave 0..3 -> rows wv*16..+16
  const int l15  = lane & 15;
  const int g    = lane >> 4;          // k-group / row-subgroup
  const int row0 = blockIdx.x * 64;

  const int sr = tid >> 4;             // staging row 0..15 (+i*16)
  const int sq = tid & 15;             // staging k-quad (4 floats)

  f32x4 acc[4] = {};
  float4 pa[4], pb[4];

  constexpr int NCH = DM / 64;         // 16 K-chunks
  #pragma unroll
  for (int i = 0; i < 4; ++i) {
    const int r = sr + i * 16;
    pa[i] = *reinterpret_cast<const float4*>(&u[(long)(row0 + r) * DM + sq * 4]);
    pb[i] = *reinterpret_cast<const float4*>(&Bm[(long)r * DM + sq * 4]);
  }

  for (int c = 0; c < NCH; ++c) {
    const int buf = c & 1;
    if (c) __syncthreads();
    #pragma unroll
    for (int i = 0; i < 4; ++i) {
      const int r = sr + i * 16;
      ushort4 ha = make_ushort4(f2bf(pa[i].x), f2bf(pa[i].y), f2bf(pa[i].z), f2bf(pa[i].w));
      ushort4 hb = make_ushort4(f2bf(pb[i].x), f2bf(pb[i].y), f2bf(pb[i].z), f2bf(pb[i].w));
      *reinterpret_cast<ushort4*>(&As[buf][r][sq * 4]) = ha;
      *reinterpret_cast<ushort4*>(&Bs[buf][r][sq * 4]) = hb;
    }
    __syncthreads();
    if (c + 1 < NCH) {                 // prefetch next chunk (hides under MFMA)
      const int kb = (c + 1) * 64;
      #pragma unroll
      for (int i = 0; i < 4; ++i) {
        const int r = sr + i * 16;
        pa[i] = *reinterpret_cast<const float4*>(&u[(long)(row0 + r) * DM + kb + sq * 4]);
        pb[i] = *reinterpret_cast<const float4*>(&Bm[(long)r * DM + kb + sq * 4]);
      }
    }
    #pragma unroll
    for (int ks = 0; ks < 2; ++ks) {
      const bf16x8 af = *reinterpret_cast<const bf16x8*>(
          &As[buf][wv * 16 + l15][ks * 32 + g * 8]);
      #pragma unroll
      for (int t = 0; t < 4; ++t) {
        const bf16x8 bfr = *reinterpret_cast<const bf16x8*>(
            &Bs[buf][t * 16 + l15][ks * 32 + g * 8]);
        acc[t] = __builtin_amdgcn_mfma_f32_16x16x32_bf16(af, bfr, acc[t], 0, 0, 0);
      }
    }
  }

  // Bu tile -> LDS transpose. D-frag: col n = t*16+l15, row = wv*16 + g*4 + r.
  __syncthreads();                     // all waves done reading As/Bs (union with T)
  #pragma unroll
  for (int t = 0; t < 4; ++t)
    #pragma unroll
    for (int r = 0; r < 4; ++r)
      T[wv * 16 + g * 4 + r][t * 16 + l15] = acc[t][r];
  __syncthreads();

  // wave 0: per-n 64-step scan in registers; write xs-local f32 + chunk final.
  if (tid < 64) {
    const int n = tid;
    const float dt = __expf(log_dt[0]);
    const float a  = __expf(-dt * __expf(Lambda[n]));
    float v[CHUNK];
    #pragma unroll
    for (int s = 0; s < CHUNK; ++s) v[s] = T[s][n];   // 2-way LDS = free
    const long base = (long)row0 * N + n;
    float x = 0.0f;
    #pragma unroll
    for (int s = 0; s < CHUNK; ++s) {
      x = fmaf(a, x, v[s]);
      xs[base + s * N] = x;            // 256 B/wave segments, coalesced
    }
    F[blockIdx.x * N + n] = x;         // blockIdx.x == b*NCHUNK + c
  }
}

// ---------------- Kernel 2: carry over chunk finals ---------------------------
__global__ __launch_bounds__(256) void carry_scan(const float* __restrict__ F,
                                                  const float* __restrict__ Lambda,
                                                  const float* __restrict__ log_dt,
                                                  float* __restrict__ carry) {
  const int t = threadIdx.x;
  const int b = t >> 6;
  const int n = t & 63;
  const float dt = __expf(log_dt[0]);
  const float w  = -dt * __expf(Lambda[n]);
  const float aS = __expf(w * (float)CHUNK);

  float f[NCHUNK];
  #pragma unroll
  for (int c = 0; c < NCHUNK; ++c) f[c] = F[(b * NCHUNK + c) * N + n];

  float P = 0.0f;
  #pragma unroll
  for (int c = 0; c < NCHUNK; ++c) {
    carry[(b * NCHUNK + c) * N + n] = P;
    P = fmaf(aS, P, f[c]);
  }
}

// ---------------- Kernel 3: y = (xs_local + dec*carry) @ C.T (+D*u if D!=0) ---
// Tile 64 rows (= one chunk) x 128 d. Carry fixup + bf16 convert fused into
// Xs staging; C converted from f32 in staging (L2/L3-hot). LDS-transpose
// epilogue -> coalesced float4 stores.
__global__ __launch_bounds__(256) void y_gemm(const float* __restrict__ xs,
                                              const float* __restrict__ carry,
                                              const float* __restrict__ Lambda,
                                              const float* __restrict__ log_dt,
                                              const float* __restrict__ Cm,
                                              const float* __restrict__ Dv,
                                              const float* __restrict__ u,
                                              float* __restrict__ y) {
  __shared__ __align__(16) char smem[33792];
  unsigned short (*Xs)[72] = reinterpret_cast<unsigned short (*)[72]>(smem);         // 9216 B
  unsigned short (*Cs)[72] = reinterpret_cast<unsigned short (*)[72]>(smem + 9216);  // 18432 B
  float (*T)[132] = reinterpret_cast<float (*)[132]>(smem);                          // 33792 B union
  __shared__ float wS[64], ciS[64], Dsh[128];

  const int tid  = threadIdx.x;
  const int lane = tid & 63;
  const int wv   = tid >> 6;
  const int l15  = lane & 15;
  const int g    = lane >> 4;
  const int row0 = (blockIdx.x & 255) * 64;
  const int d0   = (blockIdx.x >> 8) * 128;

  if (tid < 64) {
    const float dt = __expf(log_dt[0]);
    wS[tid]  = -dt * __expf(Lambda[tid]);
    ciS[tid] = carry[row0 + tid];      // (row0>>6)*64 + n == row0 + n
  }
  if (tid < 128) Dsh[tid] = Dv[d0 + tid];
  __syncthreads();

  // stage Xs with carry fixup: 64 rows x 64 n f32 -> bf16 (4 float4/thread)
  #pragma unroll
  for (int i = 0; i < 4; ++i) {
    const int idx = tid + i * 256;
    const int r = idx >> 4, q = idx & 15;
    float4 v = *reinterpret_cast<const float4*>(&xs[(long)(row0 + r) * N + q * 4]);
    const float p = (float)(r + 1);
    v.x += __expf(wS[q * 4 + 0] * p) * ciS[q * 4 + 0];
    v.y += __expf(wS[q * 4 + 1] * p) * ciS[q * 4 + 1];
    v.z += __expf(wS[q * 4 + 2] * p) * ciS[q * 4 + 2];
    v.w += __expf(wS[q * 4 + 3] * p) * ciS[q * 4 + 3];
    *reinterpret_cast<ushort4*>(&Xs[r][q * 4]) =
        make_ushort4(f2bf(v.x), f2bf(v.y), f2bf(v.z), f2bf(v.w));
  }
  // stage Cs from f32: 128 d x 64 n (8 float4/thread)
  #pragma unroll
  for (int i = 0; i < 8; ++i) {
    const int idx = tid + i * 256;
    const int r = idx >> 4, q = idx & 15;
    const float4 v = *reinterpret_cast<const float4*>(&Cm[(long)(d0 + r) * N + q * 4]);
    *reinterpret_cast<ushort4*>(&Cs[r][q * 4]) =
        make_ushort4(f2bf(v.x), f2bf(v.y), f2bf(v.z), f2bf(v.w));
  }
  __syncthreads();

  bf16x8 af[2];
  #pragma unroll
  for (int ks = 0; ks < 2; ++ks)
    af[ks] = *reinterpret_cast<const bf16x8*>(&Xs[wv * 16 + l15][ks * 32 + g * 8]);

  f32x4 acc[8] = {};
  #pragma unroll
  for (int t = 0; t < 8; ++t) {
    #pragma unroll
    for (int ks = 0; ks < 2; ++ks) {
      const bf16x8 bfr = *reinterpret_cast<const bf16x8*>(
          &Cs[t * 16 + l15][ks * 32 + g * 8]);
      acc[t] = __builtin_amdgcn_mfma_f32_16x16x32_bf16(af[ks], bfr, acc[t], 0, 0, 0);
    }
  }

  // transpose via LDS (acc: col = d0 + t*16+l15, rows wv*16+g*4..+3)
  __syncthreads();                     // staging fully consumed; safe to overwrite
  #pragma unroll
  for (int t = 0; t < 8; ++t)
    #pragma unroll
    for (int r = 0; r < 4; ++r)
      T[wv * 16 + g * 4 + r][t * 16 + l15] = acc[t][r];
  __syncthreads();

  // coalesced float4 stores: 2048 quads over 256 threads
  #pragma unroll
  for (int i = 0; i < 8; ++i) {
    const int id = tid + i * 256;
    const int r = id >> 5;             // 0..63
    const int q = id & 31;             // col-quad 0..31
    float4 v = *reinterpret_cast<const float4*>(&T[r][q * 4]);
    const float4 dd = *reinterpret_cast<const float4*>(&Dsh[q * 4]);
    if (dd.x != 0.0f || dd.y != 0.0f || dd.z != 0.0f || dd.w != 0.0f) {
      const float4 uu = *reinterpret_cast<const float4*>(
          &u[(long)(row0 + r) * DM + d0 + q * 4]);
      v.x = fmaf(dd.x, uu.x, v.x);
      v.y = fmaf(dd.y, uu.y, v.y);
      v.z = fmaf(dd.z, uu.z, v.z);
      v.w = fmaf(dd.w, uu.w, v.w);
    }
    *reinterpret_cast<float4*>(&y[(long)(row0 + r) * DM + d0 + q * 4]) = v;
  }
}

extern "C" void kernel_launch(void* const* d_in, const int* in_sizes, int n_in,
                              void* d_out, int out_size, void* d_ws, size_t ws_size,
                              hipStream_t stream) {
  const float* u      = (const float*)d_in[0];
  const float* Lambda = (const float*)d_in[1];
  const float* log_dt = (const float*)d_in[2];
  const float* Bm     = (const float*)d_in[3];
  const float* Cm     = (const float*)d_in[4];
  const float* Dv     = (const float*)d_in[5];
  float* y = (float*)d_out;

  const size_t planeB = (size_t)ROWS * N;            // 1M floats = 4 MB
  float* xs    = (float*)d_ws;                       // 4 MB
  float* F     = xs + planeB;                        // 64 KB
  float* carry = F + (size_t)BATCH * NCHUNK * N;     // 64 KB

  bu_scan<<<ROWS / 64, 256, 0, stream>>>(u, Bm, Lambda, log_dt, xs, F);
  carry_scan<<<1, 256, 0, stream>>>(F, Lambda, log_dt, carry);
  y_gemm<<<(ROWS / 64) * (DM / 128), 256, 0, stream>>>(xs, carry, Lambda, log_dt,
                                                       Cm, Dv, u, y);
}